// Round 2
// baseline (286.169 us; speedup 1.0000x reference)
//
#include <hip/hip_runtime.h>
#include <hip/hip_bf16.h>

#define NH 32
#define NKVH 8
#define HD 128

typedef __attribute__((ext_vector_type(8))) __bf16 bf16x8;
typedef __attribute__((ext_vector_type(4))) float f32x4;
typedef __attribute__((ext_vector_type(2))) unsigned int u32x2;
typedef __attribute__((ext_vector_type(4))) unsigned int u32x4;

__device__ inline unsigned short f2bf(float f) {
    unsigned int u = __builtin_bit_cast(unsigned int, f);
    u += 0x7fffu + ((u >> 16) & 1u);   // RNE
    return (unsigned short)(u >> 16);
}
__device__ inline unsigned int pk2(float lo, float hi) {
    return (unsigned int)f2bf(lo) | ((unsigned int)f2bf(hi) << 16);
}
__device__ inline f32x4 mfma16(bf16x8 a, bf16x8 b, f32x4 c) {
    return __builtin_amdgcn_mfma_f32_16x16x32_bf16(a, b, c, 0, 0, 0);
}

// ---- prep 1: K f32 -> bf16, same flat [T][NKVH*HD] layout
__global__ __launch_bounds__(256) void prep_k(const float* __restrict__ kg,
                                              unsigned short* __restrict__ kb,
                                              int nunits) {
    int u = blockIdx.x * 256 + threadIdx.x;
    if (u >= nunits) return;
    const float* p = kg + (size_t)u * 8;
    f32x4 a = *(const f32x4*)p;
    f32x4 b = *(const f32x4*)(p + 4);
    u32x4 r = {pk2(a[0], a[1]), pk2(a[2], a[3]), pk2(b[0], b[1]), pk2(b[2], b[3])};
    *(u32x4*)(kb + (size_t)u * 8) = r;
}

// ---- prep 2: V f32 -> bf16 transposed ragged: VT[b][kvh][d][j], row stride = L_b
__global__ __launch_bounds__(256) void prep_vt(const float* __restrict__ vg,
                                               const int* __restrict__ cu,
                                               unsigned short* __restrict__ vt) {
    const int b = blockIdx.y, kvh = blockIdx.z;
    const int bstart = cu[b];
    const int L = cu[b + 1] - bstart;
    const int kv0 = blockIdx.x * 64;
    if (kv0 >= L) return;
    const int tid = threadIdx.x;
    const int wid = tid >> 6, lane = tid & 63;
    __shared__ __align__(16) unsigned short Vl[HD * 64];

    #pragma unroll
    for (int it = 0; it < 4; ++it) {
        int jp = wid * 8 + (lane >> 3);
        int c4 = (lane & 7) + it * 8;
        int j0 = jp * 2;
        int jj0 = kv0 + j0;
        f32x4 va = f32x4{0.f, 0.f, 0.f, 0.f}, vb = f32x4{0.f, 0.f, 0.f, 0.f};
        if (jj0 < L)     va = *(const f32x4*)&vg[(size_t)(bstart + jj0) * (NKVH * HD) + kvh * HD + c4 * 4];
        if (jj0 + 1 < L) vb = *(const f32x4*)&vg[(size_t)(bstart + jj0 + 1) * (NKVH * HD) + kvh * HD + c4 * 4];
        #pragma unroll
        for (int i = 0; i < 4; ++i) {
            int d = c4 * 4 + i;
            int idx = (d * 64 + j0) ^ ((d & 7) << 3);
            *(unsigned int*)&Vl[idx] = pk2(va[i], vb[i]);
        }
    }
    __syncthreads();

    const int vtb = bstart * (NKVH * HD) + kvh * (HD * L);
    #pragma unroll
    for (int it = 0; it < 8; ++it) {
        int u = tid + it * 256;          // 2048 units of 4 elems
        int d = u >> 4, c = u & 15;
        int j0 = c * 4;
        if (kv0 + j0 >= L) continue;
        int idx = d * 64 + (j0 ^ ((d & 7) << 3));
        u32x2 w = *(const u32x2*)&Vl[idx];
        *(u32x2*)&vt[vtb + d * L + kv0 + j0] = w;
    }
}

// ---- attention: no K/V LDS staging, no barriers; wave = 32 q-rows of one head
__global__ __launch_bounds__(256) void fa2(const float* __restrict__ qg,
                                           const unsigned short* __restrict__ kb,
                                           const unsigned short* __restrict__ vt,
                                           const int* __restrict__ cu,
                                           float* __restrict__ outg) {
    const int b = blockIdx.y, h = blockIdx.z;
    const int bstart = cu[b];
    const int L = cu[b + 1] - bstart;
    const int tid = threadIdx.x;
    const int wid = tid >> 6, lane = tid & 63;
    const int lg = lane >> 4, lr = lane & 15;
    const int qw0 = blockIdx.x * 128 + wid * 32;
    if (qw0 >= L) return;
    const int kvh = h >> 2;
    const int vtb = bstart * (NKVH * HD) + kvh * (HD * L);

    __shared__ unsigned short Plds[4][32 * 72];   // per-wave P, stride 72 (no pow2 bank pattern)
    unsigned short* Pw = Plds[wid];

    bf16x8 qf[2][4];
    #pragma unroll
    for (int rt = 0; rt < 2; ++rt) {
        int row = qw0 + rt * 16 + lr;
        int tok = bstart + (row < L ? row : L - 1);
        #pragma unroll
        for (int kk = 0; kk < 4; ++kk) {
            const float* p = &qg[(size_t)tok * (NH * HD) + h * HD + kk * 32 + lg * 8];
            f32x4 a = *(const f32x4*)p;
            f32x4 bq = *(const f32x4*)(p + 4);
            u32x4 r = {pk2(a[0], a[1]), pk2(a[2], a[3]), pk2(bq[0], bq[1]), pk2(bq[2], bq[3])};
            qf[rt][kk] = __builtin_bit_cast(bf16x8, r);
        }
    }

    f32x4 acc[2][8];
    #pragma unroll
    for (int rt = 0; rt < 2; ++rt)
        #pragma unroll
        for (int i = 0; i < 8; ++i) acc[rt][i] = f32x4{0.f, 0.f, 0.f, 0.f};
    float mrun[2][4], lrun[2][4];
    #pragma unroll
    for (int rt = 0; rt < 2; ++rt)
        #pragma unroll
        for (int r = 0; r < 4; ++r) { mrun[rt][r] = -1e30f; lrun[rt][r] = 0.f; }

    const float sc = 0.08838834764831843f * 1.4426950408889634f; // 1/sqrt(128)*log2(e)
    const int kvmax = (qw0 + 32 < L) ? qw0 + 32 : L;
    const int ntiles = (kvmax + 63) >> 6;

    for (int kt = 0; kt < ntiles; ++kt) {
        const int kv0 = kt * 64;

        // ---- S = Q K^T : B-frags straight from global (L2-resident bf16 K)
        f32x4 sv[2][4];
        #pragma unroll
        for (int rt = 0; rt < 2; ++rt)
            #pragma unroll
            for (int s = 0; s < 4; ++s) sv[rt][s] = f32x4{0.f, 0.f, 0.f, 0.f};
        #pragma unroll
        for (int s = 0; s < 4; ++s) {
            int jj = kv0 + s * 16 + lr;
            int jtok = bstart + (jj < L ? jj : L - 1);
            const unsigned short* kp = &kb[(size_t)jtok * (NKVH * HD) + kvh * HD + lg * 8];
            #pragma unroll
            for (int kk = 0; kk < 4; ++kk) {
                bf16x8 kf = *(const bf16x8*)(kp + kk * 32);
                sv[0][s] = mfma16(qf[0][kk], kf, sv[0][s]);
                sv[1][s] = mfma16(qf[1][kk], kf, sv[1][s]);
            }
        }

        // ---- online softmax per row-tile (rows = rt*16 + lg*4 + r, cols = lr)
        #pragma unroll
        for (int rt = 0; rt < 2; ++rt) {
            const int qposb = qw0 + rt * 16 + lg * 4;
            float tmax[4];
            #pragma unroll
            for (int r = 0; r < 4; ++r) tmax[r] = -1e30f;
            #pragma unroll
            for (int s = 0; s < 4; ++s) {
                int kpos = kv0 + s * 16 + lr;
                #pragma unroll
                for (int r = 0; r < 4; ++r) {
                    float x = sv[rt][s][r] * sc;
                    x = (kpos <= qposb + r) ? x : -1e30f;
                    sv[rt][s][r] = x;
                    tmax[r] = fmaxf(tmax[r], x);
                }
            }
            #pragma unroll
            for (int r = 0; r < 4; ++r) {
                float t = tmax[r];
                t = fmaxf(t, __shfl_xor(t, 1));
                t = fmaxf(t, __shfl_xor(t, 2));
                t = fmaxf(t, __shfl_xor(t, 4));
                t = fmaxf(t, __shfl_xor(t, 8));
                float newm = fmaxf(mrun[rt][r], t);
                tmax[r] = exp2f(mrun[rt][r] - newm);   // alpha
                mrun[rt][r] = newm;
            }
            float rsum[4] = {0.f, 0.f, 0.f, 0.f};
            #pragma unroll
            for (int s = 0; s < 4; ++s) {
                #pragma unroll
                for (int r = 0; r < 4; ++r) {
                    float p = exp2f(sv[rt][s][r] - mrun[rt][r]);
                    sv[rt][s][r] = p;
                    rsum[r] += p;
                }
            }
            #pragma unroll
            for (int r = 0; r < 4; ++r) {
                float t = rsum[r];
                t += __shfl_xor(t, 1);
                t += __shfl_xor(t, 2);
                t += __shfl_xor(t, 4);
                t += __shfl_xor(t, 8);
                lrun[rt][r] = lrun[rt][r] * tmax[r] + t;
            }
            #pragma unroll
            for (int dsb = 0; dsb < 8; ++dsb)
                #pragma unroll
                for (int r = 0; r < 4; ++r) acc[rt][dsb][r] *= tmax[r];
            // P -> wave-local LDS (bf16)
            #pragma unroll
            for (int s = 0; s < 4; ++s)
                #pragma unroll
                for (int r = 0; r < 4; ++r) {
                    int prow = rt * 16 + lg * 4 + r;
                    Pw[prow * 72 + s * 16 + lr] = f2bf(sv[rt][s][r]);
                }
        }

        // ---- O += P V : V^T B-frags straight from global
        #pragma unroll
        for (int jc = 0; jc < 2; ++jc) {
            bf16x8 pa0 = *(const bf16x8*)&Pw[(lr) * 72 + jc * 32 + lg * 8];
            bf16x8 pa1 = *(const bf16x8*)&Pw[(16 + lr) * 72 + jc * 32 + lg * 8];
            #pragma unroll
            for (int dsb = 0; dsb < 8; ++dsb) {
                const unsigned short* vp = &vt[vtb + (dsb * 16 + lr) * L + kv0 + jc * 32 + lg * 8];
                bf16x8 vf = *(const bf16x8*)vp;
                acc[0][dsb] = mfma16(pa0, vf, acc[0][dsb]);
                acc[1][dsb] = mfma16(pa1, vf, acc[1][dsb]);
            }
        }
    }

    // ---- epilogue
    #pragma unroll
    for (int rt = 0; rt < 2; ++rt)
        #pragma unroll
        for (int r = 0; r < 4; ++r) {
            int row = qw0 + rt * 16 + lg * 4 + r;
            if (row >= L) continue;
            float inv = 1.0f / lrun[rt][r];
            size_t base = (size_t)(bstart + row) * (NH * HD) + h * HD + lr;
            #pragma unroll
            for (int dsb = 0; dsb < 8; ++dsb)
                outg[base + dsb * 16] = acc[rt][dsb][r] * inv;
        }
}

extern "C" void kernel_launch(void* const* d_in, const int* in_sizes, int n_in,
                              void* d_out, int out_size, void* d_ws, size_t ws_size,
                              hipStream_t stream) {
    const float* q = (const float*)d_in[0];
    const float* k = (const float*)d_in[1];
    const float* v = (const float*)d_in[2];
    const int* cu  = (const int*)d_in[3];
    int T = in_sizes[0] / (NH * HD);
    int B = in_sizes[3] - 1;

    // workspace: Kb [T*1024] bf16, then VT [T*1024] bf16  (needs T*4096 bytes = 13.1 MB)
    unsigned short* kb = (unsigned short*)d_ws;
    unsigned short* vt = kb + (size_t)T * (NKVH * HD);

    int nunits = T * (NKVH * HD) / 8;
    prep_k<<<(nunits + 255) / 256, 256, 0, stream>>>(k, kb, nunits);
    dim3 gvt((T + 63) / 64, B, NKVH);
    prep_vt<<<gvt, 256, 0, stream>>>(v, cu, vt);

    dim3 grid((T + 127) / 128, B, NH);
    fa2<<<grid, dim3(256), 0, stream>>>(q, kb, vt, cu, (float*)d_out);
}

// Round 3
// 130.102 us; speedup vs baseline: 2.1996x; 2.1996x over previous
//
#include <hip/hip_runtime.h>
#include <hip/hip_bf16.h>

#define NH 32
#define NKVH 8
#define HD 128
#define KT 64   // KV tile rows
#define QB 64   // q rows per block (2 wave-groups x 32)

typedef __attribute__((ext_vector_type(8))) __bf16 bf16x8;
typedef __attribute__((ext_vector_type(4))) float f32x4;
typedef __attribute__((ext_vector_type(2))) unsigned int u32x2;
typedef __attribute__((ext_vector_type(4))) unsigned int u32x4;

__device__ inline unsigned short f2bf(float f) {
    unsigned int u = __builtin_bit_cast(unsigned int, f);
    u += 0x7fffu + ((u >> 16) & 1u);   // RNE
    return (unsigned short)(u >> 16);
}
__device__ inline unsigned int pk2(float lo, float hi) {
    return (unsigned int)f2bf(lo) | ((unsigned int)f2bf(hi) << 16);
}
__device__ inline f32x4 mfma16(bf16x8 a, bf16x8 b, f32x4 c) {
    return __builtin_amdgcn_mfma_f32_16x16x32_bf16(a, b, c, 0, 0, 0);
}
__device__ inline void async16(unsigned short* lds, const unsigned short* g) {
    __builtin_amdgcn_global_load_lds(
        (const __attribute__((address_space(1))) unsigned int*)g,
        (__attribute__((address_space(3))) unsigned int*)lds, 16, 0, 0);
}

// ---- prep 1: K f32 -> bf16, same flat [T][NKVH*HD] layout
__global__ __launch_bounds__(256) void prep_k(const float* __restrict__ kg,
                                              unsigned short* __restrict__ kb,
                                              int nunits) {
    int u = blockIdx.x * 256 + threadIdx.x;
    if (u >= nunits) return;
    const float* p = kg + (size_t)u * 8;
    f32x4 a = *(const f32x4*)p;
    f32x4 b = *(const f32x4*)(p + 4);
    u32x4 r = {pk2(a[0], a[1]), pk2(a[2], a[3]), pk2(b[0], b[1]), pk2(b[2], b[3])};
    *(u32x4*)(kb + (size_t)u * 8) = r;
}

// ---- prep 2: V f32 -> bf16 transposed ragged: VT[b][kvh][d][j], row stride = L_b
__global__ __launch_bounds__(256) void prep_vt(const float* __restrict__ vg,
                                               const int* __restrict__ cu,
                                               unsigned short* __restrict__ vt) {
    const int b = blockIdx.y, kvh = blockIdx.z;
    const int bstart = cu[b];
    const int L = cu[b + 1] - bstart;
    const int kv0 = blockIdx.x * 64;
    if (kv0 >= L) return;
    const int tid = threadIdx.x;
    const int wid = tid >> 6, lane = tid & 63;
    __shared__ __align__(16) unsigned short Vl[HD * 64];

    #pragma unroll
    for (int it = 0; it < 4; ++it) {
        int jp = wid * 8 + (lane >> 3);
        int c4 = (lane & 7) + it * 8;
        int j0 = jp * 2;
        int jj0 = kv0 + j0;
        f32x4 va = f32x4{0.f, 0.f, 0.f, 0.f}, vb = f32x4{0.f, 0.f, 0.f, 0.f};
        if (jj0 < L)     va = *(const f32x4*)&vg[(size_t)(bstart + jj0) * (NKVH * HD) + kvh * HD + c4 * 4];
        if (jj0 + 1 < L) vb = *(const f32x4*)&vg[(size_t)(bstart + jj0 + 1) * (NKVH * HD) + kvh * HD + c4 * 4];
        #pragma unroll
        for (int i = 0; i < 4; ++i) {
            int d = c4 * 4 + i;
            int idx = (d * 64 + j0) ^ ((d & 7) << 3);
            *(unsigned int*)&Vl[idx] = pk2(va[i], vb[i]);
        }
    }
    __syncthreads();

    const size_t vtb = (size_t)bstart * (NKVH * HD) + (size_t)kvh * HD * L;
    #pragma unroll
    for (int it = 0; it < 8; ++it) {
        int u = tid + it * 256;          // 2048 units of 4 elems
        int d = u >> 4, c = u & 15;
        int j0 = c * 4;
        if (kv0 + j0 >= L) continue;
        int idx = d * 64 + (j0 ^ ((d & 7) << 3));
        u32x2 w = *(const u32x2*)&Vl[idx];
        *(u32x2*)&vt[vtb + (size_t)d * L + kv0 + j0] = w;
    }
}

// ---- fused attention: GQA-shared LDS staging, 8 waves = 4 heads x 2 row-groups
__global__ __launch_bounds__(512, 2) void fa3(const float* __restrict__ qg,
                                              const unsigned short* __restrict__ kb,
                                              const unsigned short* __restrict__ vt,
                                              const int* __restrict__ cu,
                                              float* __restrict__ outg) {
    const int b = blockIdx.y, kvh = blockIdx.z;
    const int bstart = cu[b];
    const int L = cu[b + 1] - bstart;
    const int qt = (gridDim.x - 1) - blockIdx.x;   // big blocks first
    const int q0 = qt * QB;
    if (q0 >= L) return;

    const int tid = threadIdx.x;
    const int wid = tid >> 6, lane = tid & 63;
    const int lg = lane >> 4, lr = lane & 15;
    const int h = kvh * 4 + (wid & 3);
    const int qg0 = q0 + (wid >> 2) * 32;          // this wave's 32-row base

    __shared__ __align__(16) unsigned short Klds[KT * HD];     // 16 KB
    __shared__ __align__(16) unsigned short Vlds[HD * KT];     // 16 KB
    __shared__ __align__(16) unsigned short Plds[8][32 * 64];  // 32 KB
    unsigned short* Pw = Plds[wid];

    // ---- Q fragments (A-frag: row=lr, k=lg*8+i per 32-slice)
    bf16x8 qf[2][4];
    #pragma unroll
    for (int rt = 0; rt < 2; ++rt) {
        int row = qg0 + rt * 16 + lr;
        int tok = bstart + (row < L ? row : L - 1);
        #pragma unroll
        for (int kk = 0; kk < 4; ++kk) {
            const float* p = &qg[(size_t)tok * (NH * HD) + h * HD + kk * 32 + lg * 8];
            f32x4 a = *(const f32x4*)p;
            f32x4 bq = *(const f32x4*)(p + 4);
            u32x4 r = {pk2(a[0], a[1]), pk2(a[2], a[3]), pk2(bq[0], bq[1]), pk2(bq[2], bq[3])};
            qf[rt][kk] = __builtin_bit_cast(bf16x8, r);
        }
    }

    f32x4 acc[2][8];
    #pragma unroll
    for (int rt = 0; rt < 2; ++rt)
        #pragma unroll
        for (int i = 0; i < 8; ++i) acc[rt][i] = f32x4{0.f, 0.f, 0.f, 0.f};
    float mrun[2][4], lrun[2][4];
    #pragma unroll
    for (int rt = 0; rt < 2; ++rt)
        #pragma unroll
        for (int r = 0; r < 4; ++r) { mrun[rt][r] = -1e30f; lrun[rt][r] = 0.f; }

    const float sc = 0.08838834764831843f * 1.4426950408889634f; // 1/sqrt(128)*log2(e)
    const int myqmax = (qg0 + 32 < L) ? qg0 + 32 : L;
    const int qmaxb = (q0 + QB < L) ? q0 + QB : L;
    const int ntiles = (qmaxb + KT - 1) / KT;

    const unsigned short* kbase = kb + (size_t)bstart * (NKVH * HD) + kvh * HD;
    const unsigned short* vbase = vt + (size_t)bstart * (NKVH * HD) + (size_t)kvh * HD * L;

    for (int kt = 0; kt < ntiles; ++kt) {
        const int kv0 = kt * KT;

        // ---- stage K tile: LDS dest linear, global source pre-swizzled (rule #21)
        #pragma unroll
        for (int i = 0; i < 2; ++i) {
            int U = i * 512 + tid;               // 16B unit index, 1024 units
            int j = U >> 4, u = U & 15;
            int up = (u & 8) | ((u ^ j) & 7);
            int jj = kv0 + j; if (jj >= L) jj = L - 1;
            async16(Klds + (size_t)U * 8, kbase + (size_t)jj * (NKVH * HD) + up * 8);
        }
        // ---- stage V^T tile
        #pragma unroll
        for (int i = 0; i < 2; ++i) {
            int U = i * 512 + tid;
            int d = U >> 3, u = U & 7;
            int up = u ^ (d & 7);
            int col = kv0 + up * 8;
            if (col > L - 8) col = L - 8;
            async16(Vlds + (size_t)U * 8, vbase + (size_t)d * L + col);
        }
        __syncthreads();   // drains vmcnt -> tiles resident

        if (kv0 < myqmax) {
            // ---- S = Q K^T (swizzled ds_read_b128)
            f32x4 sv[2][4];
            #pragma unroll
            for (int rt = 0; rt < 2; ++rt)
                #pragma unroll
                for (int s = 0; s < 4; ++s) sv[rt][s] = f32x4{0.f, 0.f, 0.f, 0.f};
            #pragma unroll
            for (int s = 0; s < 4; ++s) {
                int row = s * 16 + lr;
                #pragma unroll
                for (int kk = 0; kk < 4; ++kk) {
                    int un = kk * 4 + lg;
                    int cs = ((un & 8) | ((un ^ row) & 7)) * 8;
                    bf16x8 kf = *(const bf16x8*)&Klds[row * HD + cs];
                    sv[0][s] = mfma16(qf[0][kk], kf, sv[0][s]);
                    sv[1][s] = mfma16(qf[1][kk], kf, sv[1][s]);
                }
            }

            const bool needmask = (kv0 + KT - 1) > qg0;   // any kpos can exceed min qpos
            #pragma unroll
            for (int rt = 0; rt < 2; ++rt) {
                const int qposb = qg0 + rt * 16 + lg * 4;
                float tmax[4];
                #pragma unroll
                for (int r = 0; r < 4; ++r) tmax[r] = -1e30f;
                #pragma unroll
                for (int s = 0; s < 4; ++s) {
                    int kpos = kv0 + s * 16 + lr;
                    #pragma unroll
                    for (int r = 0; r < 4; ++r) {
                        float x = sv[rt][s][r] * sc;
                        if (needmask && kpos > qposb + r) x = -1e30f;
                        sv[rt][s][r] = x;
                        tmax[r] = fmaxf(tmax[r], x);
                    }
                }
                #pragma unroll
                for (int r = 0; r < 4; ++r) {
                    float t = tmax[r];
                    t = fmaxf(t, __shfl_xor(t, 1));
                    t = fmaxf(t, __shfl_xor(t, 2));
                    t = fmaxf(t, __shfl_xor(t, 4));
                    t = fmaxf(t, __shfl_xor(t, 8));
                    float newm = fmaxf(mrun[rt][r], t);
                    tmax[r] = __builtin_amdgcn_exp2f(mrun[rt][r] - newm);  // alpha
                    mrun[rt][r] = newm;
                }
                float rsum[4] = {0.f, 0.f, 0.f, 0.f};
                #pragma unroll
                for (int s = 0; s < 4; ++s) {
                    #pragma unroll
                    for (int r = 0; r < 4; ++r) {
                        float p = __builtin_amdgcn_exp2f(sv[rt][s][r] - mrun[rt][r]);
                        sv[rt][s][r] = p;
                        rsum[r] += p;
                    }
                }
                #pragma unroll
                for (int r = 0; r < 4; ++r) {
                    float t = rsum[r];
                    t += __shfl_xor(t, 1);
                    t += __shfl_xor(t, 2);
                    t += __shfl_xor(t, 4);
                    t += __shfl_xor(t, 8);
                    lrun[rt][r] = lrun[rt][r] * tmax[r] + t;
                }
                #pragma unroll
                for (int dsb = 0; dsb < 8; ++dsb)
                    #pragma unroll
                    for (int r = 0; r < 4; ++r) acc[rt][dsb][r] *= tmax[r];
                // P -> wave-local LDS (bf16, swizzled)
                #pragma unroll
                for (int s = 0; s < 4; ++s)
                    #pragma unroll
                    for (int r = 0; r < 4; ++r) {
                        int prow = rt * 16 + lg * 4 + r;
                        Pw[prow * 64 + ((s * 16 + lr) ^ ((prow & 7) << 3))] = f2bf(sv[rt][s][r]);
                    }
            }

            // ---- O += P V
            #pragma unroll
            for (int jc = 0; jc < 2; ++jc) {
                bf16x8 pa0 = *(const bf16x8*)&Pw[lr * 64 + ((jc * 32 + lg * 8) ^ ((lr & 7) << 3))];
                bf16x8 pa1 = *(const bf16x8*)&Pw[(16 + lr) * 64 + ((jc * 32 + lg * 8) ^ ((lr & 7) << 3))];
                #pragma unroll
                for (int dsb = 0; dsb < 8; ++dsb) {
                    int vrow = dsb * 16 + lr;
                    int un = jc * 4 + lg;
                    int cs = ((un ^ vrow) & 7) * 8;
                    bf16x8 vf = *(const bf16x8*)&Vlds[vrow * 64 + cs];
                    acc[0][dsb] = mfma16(pa0, vf, acc[0][dsb]);
                    acc[1][dsb] = mfma16(pa1, vf, acc[1][dsb]);
                }
            }
        }
        __syncthreads();   // compute done before next tile's staging overwrites
    }

    // ---- epilogue
    #pragma unroll
    for (int rt = 0; rt < 2; ++rt)
        #pragma unroll
        for (int r = 0; r < 4; ++r) {
            int row = qg0 + rt * 16 + lg * 4 + r;
            if (row >= L) continue;
            float inv = 1.0f / lrun[rt][r];
            size_t base = (size_t)(bstart + row) * (NH * HD) + h * HD + lr;
            #pragma unroll
            for (int dsb = 0; dsb < 8; ++dsb)
                outg[base + dsb * 16] = acc[rt][dsb][r] * inv;
        }
}

extern "C" void kernel_launch(void* const* d_in, const int* in_sizes, int n_in,
                              void* d_out, int out_size, void* d_ws, size_t ws_size,
                              hipStream_t stream) {
    const float* q = (const float*)d_in[0];
    const float* k = (const float*)d_in[1];
    const float* v = (const float*)d_in[2];
    const int* cu  = (const int*)d_in[3];
    int T = in_sizes[0] / (NH * HD);
    int B = in_sizes[3] - 1;

    // workspace: Kb [T*1024] bf16, then VT [T*1024] bf16 (13.1 MB total)
    unsigned short* kb = (unsigned short*)d_ws;
    unsigned short* vt = kb + (size_t)T * (NKVH * HD);

    int nunits = T * (NKVH * HD) / 8;
    prep_k<<<(nunits + 255) / 256, 256, 0, stream>>>(k, kb, nunits);
    dim3 gvt((T + 63) / 64, B, NKVH);
    prep_vt<<<gvt, 256, 0, stream>>>(v, cu, vt);

    dim3 grid((T + QB - 1) / QB, B, NKVH);
    fa3<<<grid, dim3(512), 0, stream>>>(q, kb, vt, cu, (float*)d_out);
}